// Round 2
// baseline (240.421 us; speedup 1.0000x reference)
//
#include <hip/hip_runtime.h>

// QTT 3D sampling, round 2: digit-grouped GEMM pipeline.
// Stages: init (C0,C1: per-sample, tiny) -> grouped GEMM stages for C2..C5
// (samples sorted by that stage's digit so blocks share the C-slice via LDS)
// -> final (C6,C7 contraction + output).
//
// Core shapes: (r_l, 8, r_{l+1}), ranks 1,8,64,256,256,256,64,8,1.
// C_l[r][d][s] at C_l[r*8*r_out + d*r_out + s].

// ---------------- prep: counting sort by digit for stages 2..5 ----------------
__global__ __launch_bounds__(256) void prep_kernel(const int* __restrict__ coords, int n,
                                                   int* __restrict__ perms /*4*n*/,
                                                   int* __restrict__ bases /*4*9*/)
{
    __shared__ int cnt[4][8];
    __shared__ int offs[4][8];
    const int t = threadIdx.x;
    if (t < 32) ((int*)cnt)[t] = 0;
    __syncthreads();
    for (int i = t; i < n; i += 256) {
        const int x = coords[3*i], y = coords[3*i+1], z = coords[3*i+2];
#pragma unroll
        for (int l = 2; l <= 5; ++l) {
            const int sh = 7 - l;
            const int d = 4*((x>>sh)&1) + 2*((y>>sh)&1) + ((z>>sh)&1);
            atomicAdd(&cnt[l-2][d], 1);
        }
    }
    __syncthreads();
    if (t < 4) {
        int run = 0;
        for (int d = 0; d < 8; ++d) {
            offs[t][d] = run;
            bases[t*9 + d] = run;
            run += cnt[t][d];
        }
        bases[t*9 + 8] = run;
    }
    __syncthreads();
    for (int i = t; i < n; i += 256) {
        const int x = coords[3*i], y = coords[3*i+1], z = coords[3*i+2];
#pragma unroll
        for (int l = 2; l <= 5; ++l) {
            const int sh = 7 - l;
            const int d = 4*((x>>sh)&1) + 2*((y>>sh)&1) + ((z>>sh)&1);
            const int pos = atomicAdd(&offs[l-2][d], 1);
            perms[(l-2)*n + pos] = i;
        }
    }
}

// ---------------- init: v8 = C0[0,d0,:], v64 = v8 . C1[:,d1,:] ----------------
__global__ __launch_bounds__(256) void init_kernel(const float* __restrict__ C0,
                                                   const float* __restrict__ C1,
                                                   const int* __restrict__ coords,
                                                   float* __restrict__ V64, int n)
{
    const int idx = blockIdx.x * 256 + threadIdx.x;
    const int i = idx >> 6, c = idx & 63;
    if (i >= n) return;
    const int x = coords[3*i], y = coords[3*i+1], z = coords[3*i+2];
    const int d0 = 4*((x>>7)&1) + 2*((y>>7)&1) + ((z>>7)&1);
    const int d1 = 4*((x>>6)&1) + 2*((y>>6)&1) + ((z>>6)&1);
    const float* a = C0 + d0*8;
    const float* B = C1 + d1*64 + c;
    float acc = 0.f;
#pragma unroll
    for (int r = 0; r < 8; ++r) acc += a[r] * B[r*512];
    V64[(size_t)i*64 + c] = acc;
}

// ---------------- grouped GEMM: Vout[perm rows] = Vin[perm rows] . C[:,d,:] ----
// Block = (digit d, 16-sample tile). Threads 256 = 16 samples x 16 col-groups.
// Thread (s,cg) computes cols {cg*4 + j*64 + i : j<N/64, i<4}.
// B LDS reads: lanes cg at 16B stride -> 2-way bank alias (free).
template<int K, int N>
__global__ __launch_bounds__(256) void stage_gemm(const float* __restrict__ Vin,
                                                  float* __restrict__ Vout,
                                                  const float* __restrict__ Ccore,
                                                  const int* __restrict__ perm,
                                                  const int* __restrict__ base)
{
    constexpr int KC = 64;          // K-chunk staged in LDS
    constexpr int NJ = N / 64;      // float4 accumulators per thread
    const int d = blockIdx.x;
    const int b0 = base[d], b1 = base[d+1];
    const int row0 = b0 + (int)blockIdx.y * 16;
    if (row0 >= b1) return;

    const int t = threadIdx.x;
    __shared__ float As[16][K + 4];     // +4 pad: samples land on distinct banks
    __shared__ float Bs[KC][N];
    __shared__ int rows[16];

    if (t < 16) {
        const int r = row0 + t;
        rows[t] = (r < b1) ? perm[r] : -1;
    }
    __syncthreads();

    // gather A tile (16 x K), zero-fill invalid rows
    {
        constexpr int NF4 = 16 * (K / 4);
        for (int idx = t; idx < NF4; idx += 256) {
            const int ri = idx / (K/4), c4 = idx % (K/4);
            float4 v = make_float4(0.f, 0.f, 0.f, 0.f);
            const int rr = rows[ri];
            if (rr >= 0) v = ((const float4*)(Vin + (size_t)rr * K))[c4];
            *(float4*)&As[ri][c4*4] = v;
        }
    }

    const float* Cd = Ccore + d * N;        // row k of slice: Cd + k*8*N
    const int s = t >> 4, cg = t & 15;
    float4 acc[NJ];
#pragma unroll
    for (int j = 0; j < NJ; ++j) acc[j] = make_float4(0.f, 0.f, 0.f, 0.f);

    for (int kc = 0; kc < K; kc += KC) {
        __syncthreads();
        // stage B chunk (KC x N)
        {
            constexpr int BF4 = KC * (N / 4);
            for (int idx = t; idx < BF4; idx += 256) {
                const int kk = idx / (N/4), c4 = idx % (N/4);
                ((float4*)Bs)[idx] =
                    ((const float4*)(Cd + (size_t)(kc + kk) * 8 * N))[c4];
            }
        }
        __syncthreads();
#pragma unroll 4
        for (int k4 = 0; k4 < KC; k4 += 4) {
            const float4 a4 = *(const float4*)&As[s][kc + k4];
#pragma unroll
            for (int kk = 0; kk < 4; ++kk) {
                const float a = (&a4.x)[kk];
#pragma unroll
                for (int j = 0; j < NJ; ++j) {
                    const float4 b = *(const float4*)&Bs[k4 + kk][cg*4 + j*64];
                    acc[j].x += a * b.x; acc[j].y += a * b.y;
                    acc[j].z += a * b.z; acc[j].w += a * b.w;
                }
            }
        }
    }

    const int rr = rows[s];
    if (rr >= 0) {
#pragma unroll
        for (int j = 0; j < NJ; ++j)
            *(float4*)(Vout + (size_t)rr * N + cg*4 + j*64) = acc[j];
    }
}

// ---------------- final: v8 = v64 . C6[:,d6,:], out = v8 . C7[:,d7,0] ----------
__global__ __launch_bounds__(256) void final_kernel(const float* __restrict__ V64,
                                                    const float* __restrict__ C6,
                                                    const float* __restrict__ C7,
                                                    const int* __restrict__ coords,
                                                    float* __restrict__ out, int n)
{
    const int t = threadIdx.x;
    const int i = blockIdx.x * 32 + (t >> 3);
    const int j = t & 7;
    if (i >= n) return;
    const int x = coords[3*i], y = coords[3*i+1], z = coords[3*i+2];
    const int d6 = 4*((x>>1)&1) + 2*((y>>1)&1) + ((z>>1)&1);
    const int d7 = 4*(x&1) + 2*(y&1) + (z&1);
    const float* v = V64 + (size_t)i*64;
    const float* B = C6 + d6*8 + j;
    float acc = 0.f;
#pragma unroll
    for (int r = 0; r < 64; ++r) acc += v[r] * B[r*64];
    float m = acc * C7[j*8 + d7];
    m += __shfl_xor(m, 1);
    m += __shfl_xor(m, 2);
    m += __shfl_xor(m, 4);
    if (j == 0) out[i] = m;
}

extern "C" void kernel_launch(void* const* d_in, const int* in_sizes, int n_in,
                              void* d_out, int out_size, void* d_ws, size_t ws_size,
                              hipStream_t stream) {
    const float* C0 = (const float*)d_in[0];
    const float* C1 = (const float*)d_in[1];
    const float* C2 = (const float*)d_in[2];
    const float* C3 = (const float*)d_in[3];
    const float* C4 = (const float*)d_in[4];
    const float* C5 = (const float*)d_in[5];
    const float* C6 = (const float*)d_in[6];
    const float* C7 = (const float*)d_in[7];
    const int* coords = (const int*)d_in[8];
    float* out = (float*)d_out;

    const int n = in_sizes[8] / 3;

    // workspace layout (~9.1 MB for n=4096)
    float* V64   = (float*)d_ws;                    // n*64
    float* V256a = V64 + (size_t)n * 64;            // n*256
    float* V256b = V256a + (size_t)n * 256;         // n*256
    int*   perms = (int*)(V256b + (size_t)n * 256); // 4*n
    int*   bases = perms + 4 * (size_t)n;           // 36

    const int ntiles = (n + 15) / 16;

    prep_kernel<<<1, 256, 0, stream>>>(coords, n, perms, bases);
    init_kernel<<<(n*64 + 255)/256, 256, 0, stream>>>(C0, C1, coords, V64, n);
    stage_gemm< 64,256><<<dim3(8, ntiles), 256, 0, stream>>>(V64,   V256a, C2, perms + 0*n, bases + 0*9);
    stage_gemm<256,256><<<dim3(8, ntiles), 256, 0, stream>>>(V256a, V256b, C3, perms + 1*n, bases + 1*9);
    stage_gemm<256,256><<<dim3(8, ntiles), 256, 0, stream>>>(V256b, V256a, C4, perms + 2*n, bases + 2*9);
    stage_gemm<256, 64><<<dim3(8, ntiles), 256, 0, stream>>>(V256a, V64,   C5, perms + 3*n, bases + 3*9);
    final_kernel<<<(n + 31)/32, 256, 0, stream>>>(V64, C6, C7, coords, out, n);
}

// Round 3
// 181.780 us; speedup vs baseline: 1.3226x; 1.3226x over previous
//
#include <hip/hip_runtime.h>

// QTT 3D sampling, round 3: digit-grouped GEMM with 4x4 micro-tile,
// wave-uniform A broadcast, async global_load_lds double-buffered B chunks.
// Core shapes: (r_l, 8, r_{l+1}), ranks 1,8,64,256,256,256,64,8,1.
// C_l[k][d][s] at C_l[k*8*r_out + d*r_out + s].

typedef unsigned int u32;

__device__ __forceinline__ void async_load16(const float* g, float* l) {
    __builtin_amdgcn_global_load_lds(
        (const __attribute__((address_space(1))) u32*)g,
        (__attribute__((address_space(3))) u32*)l, 16, 0, 0);
}

// ---------------- prep: counting sort by digit, one block per stage ----------
__global__ __launch_bounds__(256) void prep_kernel(const int* __restrict__ coords, int n,
                                                   int* __restrict__ perms,
                                                   int* __restrict__ bases)
{
    const int l = 2 + blockIdx.x;          // stage 2..5
    const int sh = 7 - l;
    __shared__ int cnt[8], offs[8];
    const int t = threadIdx.x;
    if (t < 8) cnt[t] = 0;
    __syncthreads();
    for (int i = t; i < n; i += 256) {
        const int d = 4*((coords[3*i]>>sh)&1) + 2*((coords[3*i+1]>>sh)&1)
                    + ((coords[3*i+2]>>sh)&1);
        atomicAdd(&cnt[d], 1);
    }
    __syncthreads();
    if (t == 0) {
        int run = 0;
        for (int d = 0; d < 8; ++d) {
            offs[d] = run;
            bases[(l-2)*9 + d] = run;
            run += cnt[d];
        }
        bases[(l-2)*9 + 8] = run;
    }
    __syncthreads();
    for (int i = t; i < n; i += 256) {
        const int d = 4*((coords[3*i]>>sh)&1) + 2*((coords[3*i+1]>>sh)&1)
                    + ((coords[3*i+2]>>sh)&1);
        const int pos = atomicAdd(&offs[d], 1);
        perms[(l-2)*n + pos] = i;
    }
}

// ---------------- init: v8 = C0[0,d0,:], v64 = v8 . C1[:,d1,:] ---------------
__global__ __launch_bounds__(256) void init_kernel(const float* __restrict__ C0,
                                                   const float* __restrict__ C1,
                                                   const int* __restrict__ coords,
                                                   float* __restrict__ V64, int n)
{
    const int idx = blockIdx.x * 256 + threadIdx.x;
    const int i = idx >> 6, c = idx & 63;
    if (i >= n) return;
    const int x = coords[3*i], y = coords[3*i+1], z = coords[3*i+2];
    const int d0 = 4*((x>>7)&1) + 2*((y>>7)&1) + ((z>>7)&1);
    const int d1 = 4*((x>>6)&1) + 2*((y>>6)&1) + ((z>>6)&1);
    const float* a = C0 + d0*8;
    const float* B = C1 + d1*64 + c;
    float acc = 0.f;
#pragma unroll
    for (int r = 0; r < 8; ++r) acc += a[r] * B[r*512];
    V64[(size_t)i*64 + c] = acc;
}

// ---------------- grouped GEMM stage ----------------------------------------
// Block: M=16 samples, 256 threads. N=256: thread (sg=wave, cg=t&63) computes
// 4 samples x 4 cols; A read is wave-uniform b128 broadcast, B read is lane-
// consecutive b128 (conflict-free). N=64: 4-way K-split across waves + reduce.
template<int K, int N>
__global__ __launch_bounds__(256) void stage_gemm(const float* __restrict__ Vin,
                                                  float* __restrict__ Vout,
                                                  const float* __restrict__ Ccore,
                                                  const int* __restrict__ perm,
                                                  const int* __restrict__ base)
{
    constexpr int KC   = (N == 256) ? 32 : K;   // B chunk rows in LDS
    constexpr int NCH  = K / KC;                // 8 (256x256), 2 (64x256), 1 (256x64)
    constexpr int NBUF = (NCH > 1) ? 2 : 1;
    constexpr int KP   = (N == 256) ? 1 : 4;    // K-split ways across waves
    constexpr int KPC  = KC / KP;               // rows per wave-group per chunk
    constexpr int AP   = K + 4;                 // Arm row pad

    const int d  = blockIdx.x;
    const int b0 = base[d], b1 = base[d + 1];
    const int nrows = b1 - b0;
    const int t  = threadIdx.x;
    const int ln = t & 63, wv = t >> 6;

    __shared__ float Arm[16][AP];
    __shared__ float Bs[NBUF][KC][N];
    __shared__ int   rows[16];
    __shared__ float4 red[(KP > 1) ? KP * 64 * 4 : 1];

    const float* Cd = Ccore + d * N;            // element (k, col): Cd[k*8*N + col]

    int cg, sg, kp;
    if constexpr (N == 256) { cg = t & 63; sg = wv;          kp = 0;  }
    else                    { cg = t & 15; sg = (t >> 4) & 3; kp = wv; }

    for (int tile = blockIdx.y; tile * 16 < nrows; tile += (int)gridDim.y) {
        const int row0 = b0 + tile * 16;

        // --- stage chunk 0 of B (async for N=256, reg path for N=64) ---
        if constexpr (N == 256) {
            for (int r = wv; r < KC; r += 4)
                async_load16(Cd + (size_t)r * (8 * N) + ln * 4, &Bs[0][r][ln * 4]);
        }
        if (t < 16) rows[t] = (row0 + t < b1) ? perm[row0 + t] : -1;
        if constexpr (N == 64) {
#pragma unroll
            for (int j = 0; j < (KC * N / 4) / 256; ++j) {
                const int idx = t + 256 * j, r = idx >> 4, c4 = idx & 15;
                *(float4*)&Bs[0][r][c4 * 4] =
                    *(const float4*)(Cd + (size_t)r * (8 * N) + c4 * 4);
            }
        }
        __syncthreads();                         // rows visible

        // --- gather A tile (16 x K), coalesced float4, zero-fill tails ---
        {
            constexpr int NF4 = 16 * (K / 4);
#pragma unroll
            for (int j = 0; j < NF4 / 256; ++j) {
                const int idx = t + 256 * j, s = idx / (K / 4), c4 = idx % (K / 4);
                float4 v = make_float4(0.f, 0.f, 0.f, 0.f);
                const int rr = rows[s];
                if (rr >= 0) v = *(const float4*)(Vin + (size_t)rr * K + c4 * 4);
                *(float4*)&Arm[s][c4 * 4] = v;
            }
        }
        __syncthreads();                         // Arm + B chunk0 ready (drains vmcnt)

        float4 acc[4];
#pragma unroll
        for (int i = 0; i < 4; ++i) acc[i] = make_float4(0.f, 0.f, 0.f, 0.f);

        for (int c = 0; c < NCH; ++c) {
            if constexpr (NCH > 1) {
                if (c + 1 < NCH) {
                    const int nb = (c + 1) & 1;
                    for (int r = wv; r < KC; r += 4)
                        async_load16(Cd + (size_t)((c + 1) * KC + r) * (8 * N) + ln * 4,
                                     &Bs[nb][r][ln * 4]);
                }
            }
            const int cb = (NCH > 1) ? (c & 1) : 0;
            const int kbase = c * KC;
#pragma unroll
            for (int k4 = 0; k4 < KPC; k4 += 4) {
                const int kl = kp * KPC + k4;    // row within chunk
                float4 a[4];
#pragma unroll
                for (int i = 0; i < 4; ++i)
                    a[i] = *(const float4*)&Arm[sg * 4 + i][kbase + kl];
#pragma unroll
                for (int kk = 0; kk < 4; ++kk) {
                    const float4 b = *(const float4*)&Bs[cb][kl + kk][cg * 4];
#pragma unroll
                    for (int i = 0; i < 4; ++i) {
                        const float ai = (&a[i].x)[kk];
                        acc[i].x += ai * b.x; acc[i].y += ai * b.y;
                        acc[i].z += ai * b.z; acc[i].w += ai * b.w;
                    }
                }
            }
            __syncthreads();                     // chunk c+1 ready, c readers done
        }

        if constexpr (KP == 1) {
#pragma unroll
            for (int i = 0; i < 4; ++i) {
                const int rr = rows[sg * 4 + i];
                if (rr >= 0) *(float4*)(Vout + (size_t)rr * N + cg * 4) = acc[i];
            }
        } else {
            const int u = t & 63;
#pragma unroll
            for (int i = 0; i < 4; ++i) red[(kp * 64 + u) * 4 + i] = acc[i];
            __syncthreads();
            if (t < 64) {
#pragma unroll
                for (int i = 0; i < 4; ++i) {
                    float4 s0 = red[(0 * 64 + t) * 4 + i];
                    const float4 s1 = red[(1 * 64 + t) * 4 + i];
                    const float4 s2 = red[(2 * 64 + t) * 4 + i];
                    const float4 s3 = red[(3 * 64 + t) * 4 + i];
                    s0.x += s1.x + s2.x + s3.x;
                    s0.y += s1.y + s2.y + s3.y;
                    s0.z += s1.z + s2.z + s3.z;
                    s0.w += s1.w + s2.w + s3.w;
                    const int rr = rows[sg * 4 + i];
                    if (rr >= 0) *(float4*)(Vout + (size_t)rr * N + cg * 4) = s0;
                }
            }
        }
        __syncthreads();                         // protect rows/Bs before next tile
    }
}

// ---------------- final: v8 = v64 . C6[:,d6,:], out = v8 . C7[:,d7,0] --------
__global__ __launch_bounds__(256) void final_kernel(const float* __restrict__ V64,
                                                    const float* __restrict__ C6,
                                                    const float* __restrict__ C7,
                                                    const int* __restrict__ coords,
                                                    float* __restrict__ out, int n)
{
    const int t = threadIdx.x;
    const int i = blockIdx.x * 32 + (t >> 3);
    const int j = t & 7;
    if (i >= n) return;
    const int x = coords[3*i], y = coords[3*i+1], z = coords[3*i+2];
    const int d6 = 4*((x>>1)&1) + 2*((y>>1)&1) + ((z>>1)&1);
    const int d7 = 4*(x&1) + 2*(y&1) + (z&1);
    const float* v = V64 + (size_t)i*64;
    const float* B = C6 + d6*8 + j;
    float acc = 0.f;
#pragma unroll
    for (int r = 0; r < 64; ++r) acc += v[r] * B[r*64];
    float m = acc * C7[j*8 + d7];
    m += __shfl_xor(m, 1);
    m += __shfl_xor(m, 2);
    m += __shfl_xor(m, 4);
    if (j == 0) out[i] = m;
}

extern "C" void kernel_launch(void* const* d_in, const int* in_sizes, int n_in,
                              void* d_out, int out_size, void* d_ws, size_t ws_size,
                              hipStream_t stream) {
    const float* C0 = (const float*)d_in[0];
    const float* C1 = (const float*)d_in[1];
    const float* C2 = (const float*)d_in[2];
    const float* C3 = (const float*)d_in[3];
    const float* C4 = (const float*)d_in[4];
    const float* C5 = (const float*)d_in[5];
    const float* C6 = (const float*)d_in[6];
    const float* C7 = (const float*)d_in[7];
    const int* coords = (const int*)d_in[8];
    float* out = (float*)d_out;

    const int n = in_sizes[8] / 3;

    // workspace (~9.1 MB for n=4096)
    float* V64   = (float*)d_ws;                    // n*64
    float* V256a = V64 + (size_t)n * 64;            // n*256
    float* V256b = V256a + (size_t)n * 256;         // n*256
    int*   perms = (int*)(V256b + (size_t)n * 256); // 4*n
    int*   bases = perms + 4 * (size_t)n;           // 36

    prep_kernel<<<4, 256, 0, stream>>>(coords, n, perms, bases);
    init_kernel<<<(n*64 + 255)/256, 256, 0, stream>>>(C0, C1, coords, V64, n);
    stage_gemm< 64,256><<<dim3(8,32), 256, 0, stream>>>(V64,   V256a, C2, perms + 0*n, bases + 0);
    stage_gemm<256,256><<<dim3(8,32), 256, 0, stream>>>(V256a, V256b, C3, perms + 1*n, bases + 9);
    stage_gemm<256,256><<<dim3(8,32), 256, 0, stream>>>(V256b, V256a, C4, perms + 2*n, bases + 18);
    stage_gemm<256, 64><<<dim3(8,32), 256, 0, stream>>>(V256a, V64,   C5, perms + 3*n, bases + 27);
    final_kernel<<<(n + 31)/32, 256, 0, stream>>>(V64, C6, C7, coords, out, n);
}